// Round 8
// baseline (2993.870 us; speedup 1.0000x reference)
//
#include <hip/hip_runtime.h>

#define TT 2048
#define NB 512

__device__ __forceinline__ float rcpf(float x) { return __builtin_amdgcn_rcpf(x); }
__device__ __forceinline__ float fsig(float x) { return rcpf(1.0f + __expf(-x)); }
__device__ __forceinline__ float ftanh(float x) {
    return fmaf(2.0f, rcpf(1.0f + __expf(-2.0f * x)), -1.0f);
}

template<int C>
__device__ __forceinline__ float dppmov(float s) {
    return __int_as_float(__builtin_amdgcn_update_dpp(
        __float_as_int(s), __float_as_int(s), C, 0xF, 0xF, false));
}
// Full wave64 sum, result in lane 63 (verified R6).
__device__ __forceinline__ float wave_sum63(float s) {
    s += dppmov<0x111>(s);   // row_shr:1
    s += dppmov<0x112>(s);   // row_shr:2
    s += dppmov<0x114>(s);   // row_shr:4
    s += dppmov<0x118>(s);   // row_shr:8
    s += dppmov<0x142>(s);   // row_bcast:15
    s += dppmov<0x143>(s);   // row_bcast:31
    return s;
}

// 512 blocks x 8 waves, 1 batch elem per block, 2 blocks/CU = 4 waves/SIMD.
// SPLIT-K layout: lane = 8*u' + 2*g + h. Wave owns units 8w..8w+7; the pair
// (h=0,1) splits each column's 64-long dot into two 32-FMA halves (32
// register weights/lane -> fits the 128-VGPR budget for 4 waves/SIMD).
// Pair-combine: 1 quad_perm DPP. Gate exchange: 4 ds_bpermute (__shfl),
// in-wave, no barrier. ONE __syncthreads per step. Layer-2: DPP wave_sum on
// waves 0-3 (gate=wave); scalar (c2,h2) chain ROTATES over waves 4-7 with
// state handed through an LDS parity ring (no permanent barrier straggler).
__global__ __launch_bounds__(512)
__attribute__((amdgpu_waves_per_eu(4, 4)))
void lstm2_kernel(const float* __restrict__ x,
                  const float* __restrict__ W1,
                  const float* __restrict__ b1,
                  const float* __restrict__ W2,
                  const float* __restrict__ b2,
                  float* __restrict__ out)
{
    __shared__ __align__(16) float xall[TT + 4];
    __shared__ __align__(16) float h1row[2][64];   // parity-dbuf h1 broadcast
    __shared__ __align__(16) float zp[4][4];       // layer-2 partial ring
    __shared__ __align__(16) float cs[2][2];       // chain state ring {c2,h2}
    __shared__ __align__(16) float h2buf[2][64];   // h2 staging ring

    const int tid  = threadIdx.x;
    const int wave = tid >> 6;
    const int lane = tid & 63;
    const int b    = blockIdx.x;

    for (int i = tid; i < TT; i += 512) xall[i] = x[b * TT + i];

    const int up   = lane >> 3;          // unit-in-wave 0..7
    const int g    = (lane >> 1) & 3;    // gate i,j,f,o
    const int h    = lane & 1;           // K-half
    const int unit = (wave << 3) + up;   // global unit 0..63
    const int col  = (g << 6) + unit;    // W1 (65,256) column

    // 32 h-part weights: W1 rows 1+32h .. 32+32h of this column.
#define DECLW(q) \
    const float wx##q = W1[(1 + 32*h + 4*(q) + 0) * 256 + col]; \
    const float wy##q = W1[(1 + 32*h + 4*(q) + 1) * 256 + col]; \
    const float wz##q = W1[(1 + 32*h + 4*(q) + 2) * 256 + col]; \
    const float ww##q = W1[(1 + 32*h + 4*(q) + 3) * 256 + col];
    DECLW(0) DECLW(1) DECLW(2) DECLW(3) DECLW(4) DECLW(5) DECLW(6) DECLW(7)
#undef DECLW

    const float xw    = (h == 0) ? W1[col] : 0.0f;              // x-part (half0)
    const float biasF = (h == 0) ? (b1[col] + ((g == 2) ? 1.0f : 0.0f)) : 0.0f;
    const float nlm   = (g == 1) ? -2.0f : -1.0f;
    const bool  isj   = (g == 1);
    // gate-exchange source lanes (precomputed -> bpermute index VGPRs hoisted)
    const int gb = lane & 56;
    const int li = gb, lj = gb | 2, lf = gb | 4, lo = gb | 6;

    const float w2g = W2[lane * 4 + (wave & 3)];   // used by waves 0-3
    // layer-2 chain constants (waves 4-7, lane 0)
    const float w2h0 = W2[256], w2h1 = W2[257], w2h2 = W2[258], w2h3 = W2[259];
    const float b20 = b2[0], b21 = b2[1], b22 = b2[2], b23 = b2[3];

    float c1 = 0.0f;   // redundant per 8-lane unit group

    if (tid < 64) h1row[0][tid] = 0.0f;
    if (tid < 4) ((float*)cs)[tid] = 0.0f;
    __syncthreads();

    float* __restrict__ outb = out + b * TT;

    for (int it = 0; it <= TT + 2; ++it) {
        const int p = it & 1;
        // ---- Phase A: matvec for step it from h1(it-1) = h1row[p]
        if (it < TT) {
            const float4* hp = (const float4*)&h1row[p][h << 5];  // own 32-half
            const float4 t0 = hp[0], t1 = hp[1], t2 = hp[2], t3 = hp[3];
            const float4 t4 = hp[4], t5 = hp[5], t6 = hp[6], t7 = hp[7];
            float a0 = fmaf(xall[it], xw, biasF);
            float a1 = 0.f, a2 = 0.f, a3 = 0.f;
#define FMA4(q, t) \
            a0 = fmaf(t.x, wx##q, a0); a1 = fmaf(t.y, wy##q, a1); \
            a2 = fmaf(t.z, wz##q, a2); a3 = fmaf(t.w, ww##q, a3);
            FMA4(0, t0) FMA4(1, t1) FMA4(2, t2) FMA4(3, t3)
            FMA4(4, t4) FMA4(5, t5) FMA4(6, t6) FMA4(7, t7)
#undef FMA4
            float full = (a0 + a1) + (a2 + a3);
            full += dppmov<0xB1>(full);          // quad_perm [1,0,3,2]: +pair
            // branchless nonlin (forget bias folded into biasF)
            const float e = __expf(full * nlm);
            const float r = rcpf(1.0f + e);
            const float v = isj ? fmaf(2.0f, r, -1.0f) : r;
            // in-wave gate exchange (4 bpermute, no barrier)
            const float gi = __shfl(v, li, 64);
            const float gj = __shfl(v, lj, 64);
            const float gf = __shfl(v, lf, 64);
            const float go = __shfl(v, lo, 64);
            c1 = fmaf(c1, gf, gi * gj);
            const float h1v = ftanh(c1) * go;
            if ((lane & 7) == 0) h1row[p ^ 1][unit] = h1v;
        }
        // ---- layer-2 partial for step it-1 (waves 0-3, gate = wave)
        if (wave < 4 && it >= 1 && it <= TT) {
            const float s = wave_sum63(h1row[p][lane] * w2g);
            if (lane == 63) zp[(it - 1) & 3][wave] = s;
        }
        // ---- rotating scalar chain for step st = it-2 (waves 4-7)
        if (it >= 2 && it <= TT + 1 && wave == 4 + ((it - 2) & 3) && lane == 0) {
            const int st = it - 2;
            const float4 z4 = *(const float4*)zp[st & 3];
            const float2 s2 = *(const float2*)cs[(st + 1) & 1];  // {c2,h2}(st-1)
            float c2 = s2.x, h2 = s2.y;
            const float zi = z4.x + fmaf(h2, w2h0, b20);
            const float zj = z4.y + fmaf(h2, w2h1, b21);
            const float zf = z4.z + fmaf(h2, w2h2, b22);
            const float zo = z4.w + fmaf(h2, w2h3, b23);
            c2 = c2 * fsig(zf + 1.0f) + fsig(zi) * ftanh(zj);
            h2 = ftanh(c2) * fsig(zo);
            *(float2*)cs[st & 1] = make_float2(c2, h2);
            h2buf[(st >> 6) & 1][st & 63] = h2;
        }
        __syncthreads();   // the ONLY barrier per step
        // ---- coalesced output flush: 1 store per 64 steps (wave 0)
        if (wave == 0 && it >= 66 && (it & 63) == 2) {
            const int blk = (it - 66) >> 6;
            outb[(blk << 6) + lane] = h2buf[blk & 1][lane];
        }
    }
}

extern "C" void kernel_launch(void* const* d_in, const int* in_sizes, int n_in,
                              void* d_out, int out_size, void* d_ws, size_t ws_size,
                              hipStream_t stream)
{
    const float* x  = (const float*)d_in[0];
    const float* W1 = (const float*)d_in[1];
    const float* b1 = (const float*)d_in[2];
    const float* W2 = (const float*)d_in[3];
    const float* b2 = (const float*)d_in[4];
    float* out = (float*)d_out;
    lstm2_kernel<<<NB, 512, 0, stream>>>(x, W1, b1, W2, b2, out);
}

// Round 9
// 1899.951 us; speedup vs baseline: 1.5758x; 1.5758x over previous
//
#include <hip/hip_runtime.h>

#define TT 2048
#define NB 512

__device__ __forceinline__ float rcpf(float x) { return __builtin_amdgcn_rcpf(x); }
__device__ __forceinline__ float fsig(float x) { return rcpf(1.0f + __expf(-x)); }
__device__ __forceinline__ float ftanh(float x) {
    return fmaf(2.0f, rcpf(1.0f + __expf(-2.0f * x)), -1.0f);
}

template<int C>
__device__ __forceinline__ float dppmov(float s) {
    return __int_as_float(__builtin_amdgcn_update_dpp(
        __float_as_int(s), __float_as_int(s), C, 0xF, 0xF, false));
}
// Full wave64 sum, result in lane 63 (verified R6/R8-correct).
__device__ __forceinline__ float wave_sum63(float s) {
    s += dppmov<0x111>(s);   // row_shr:1
    s += dppmov<0x112>(s);   // row_shr:2
    s += dppmov<0x114>(s);   // row_shr:4
    s += dppmov<0x118>(s);   // row_shr:8
    s += dppmov<0x142>(s);   // row_bcast:15
    s += dppmov<0x143>(s);   // row_bcast:31
    return s;
}

// 512 blocks x 2 waves (128 thr), 1 batch elem per block, 2 blocks/CU.
// TWO-COLUMN layout: wave w owns units 32w..32w+31; lane = 2*u' + gg handles
// 2 full W1 columns: gg=0 -> {i,j}, gg=1 -> {f,o} of unit u. 128 register
// weights/lane (VGPR ~170, budget 256 at waves_per_eu(2,2)). This HALVES
// per-CU LDS ops vs R6 (the theorized wall: 8 waves x 17 ds-ops ~ 1632 cyc
// ~ measured 1919 cyc/step) and halves redundant tanh/c1 work. Gate combine:
// ONE quad_perm pair-swap DPP (i*j -> odd lane which holds f,o locally);
// h1 written by odd lanes (32 conflict-free b32). ONE 2-wave barrier/step.
// Layer-2: wave w strided-reads h1 and wave-sums gates {2w,2w+1}; scalar
// chain on wave1/lane0 2-step lagged; h2 staged, flushed every 64 steps.
__global__ __launch_bounds__(128)
__attribute__((amdgpu_waves_per_eu(2, 2)))
void lstm2_kernel(const float* __restrict__ x,
                  const float* __restrict__ W1,
                  const float* __restrict__ b1,
                  const float* __restrict__ W2,
                  const float* __restrict__ b2,
                  float* __restrict__ out)
{
    __shared__ __align__(16) float xall[TT + 4];
    __shared__ __align__(16) float h1row[2][64];   // parity-dbuf h1 broadcast
    __shared__ __align__(16) float zp[4][4];       // [ring][gate] partials
    __shared__ __align__(16) float h2buf[2][64];   // h2 staging ring

    const int tid  = threadIdx.x;
    const int wave = tid >> 6;          // 0,1
    const int lane = tid & 63;
    const int b    = blockIdx.x;

    for (int i = tid; i < TT; i += 128) xall[i] = x[b * TT + i];

    const int gg   = lane & 1;                    // 0:{i,j} 1:{f,o}
    const int unit = (wave << 5) + (lane >> 1);   // global unit 0..63
    const int c0   = ((gg << 1) + 0) * 64 + unit; // col: i or f
    const int c1i  = ((gg << 1) + 1) * 64 + unit; // col: j or o

    // 128 named scalar weights: rows 1..64 (h-part) of both columns.
#define DECLWA(q) \
    const float ax##q = W1[(4*(q)+1)*256 + c0]; \
    const float ay##q = W1[(4*(q)+2)*256 + c0]; \
    const float az##q = W1[(4*(q)+3)*256 + c0]; \
    const float aw##q = W1[(4*(q)+4)*256 + c0];
#define DECLWB(q) \
    const float bx##q = W1[(4*(q)+1)*256 + c1i]; \
    const float by##q = W1[(4*(q)+2)*256 + c1i]; \
    const float bz##q = W1[(4*(q)+3)*256 + c1i]; \
    const float bw##q = W1[(4*(q)+4)*256 + c1i];
    DECLWA(0)  DECLWA(1)  DECLWA(2)  DECLWA(3)
    DECLWA(4)  DECLWA(5)  DECLWA(6)  DECLWA(7)
    DECLWA(8)  DECLWA(9)  DECLWA(10) DECLWA(11)
    DECLWA(12) DECLWA(13) DECLWA(14) DECLWA(15)
    DECLWB(0)  DECLWB(1)  DECLWB(2)  DECLWB(3)
    DECLWB(4)  DECLWB(5)  DECLWB(6)  DECLWB(7)
    DECLWB(8)  DECLWB(9)  DECLWB(10) DECLWB(11)
    DECLWB(12) DECLWB(13) DECLWB(14) DECLWB(15)
#undef DECLWA
#undef DECLWB

    const float w0a = W1[c0],  w0b = W1[c1i];     // x-part row 0
    const float ba  = b1[c0] + (gg ? 1.0f : 0.0f); // fold forget bias (f=col0 of gg=1)
    const float bb  = b1[c1i];
    // nonlin selectors: v0 always sigmoid; v1 = tanh (gg=0) or sigmoid (gg=1)
    const float nlm1 = gg ? -1.0f : -2.0f;
    const float k2   = gg ?  1.0f :  2.0f;
    const float k3   = gg ?  0.0f : -1.0f;

    const float w2a = W2[lane * 4 + (wave << 1)];      // layer-2 gate 2w
    const float w2b = W2[lane * 4 + (wave << 1) + 1];  // layer-2 gate 2w+1
    const float w2h0 = W2[256], w2h1 = W2[257], w2h2 = W2[258], w2h3 = W2[259];
    const float b20 = b2[0], b21 = b2[1], b22 = b2[2], b23 = b2[3];

    float c1 = 0.0f;                 // meaningful on odd lanes (garbage on even)
    float c2 = 0.0f, h2 = 0.0f;      // chain state (wave1/lane0)

    if (tid < 64) h1row[0][tid] = 0.0f;
    __syncthreads();

    float* __restrict__ outb = out + b * TT;

#define STEP(P, t, xv)                                                        \
    {                                                                         \
        if ((t) < TT) {                                                       \
            const float* hr = h1row[P];                                       \
            float a0 = fmaf((xv), w0a, ba), a1 = 0.f, a2 = 0.f, a3 = 0.f;     \
            float d0 = fmaf((xv), w0b, bb), d1 = 0.f, d2 = 0.f, d3 = 0.f;     \
            FMA8(0)  FMA8(1)  FMA8(2)  FMA8(3)                                \
            FMA8(4)  FMA8(5)  FMA8(6)  FMA8(7)                                \
            FMA8(8)  FMA8(9)  FMA8(10) FMA8(11)                               \
            FMA8(12) FMA8(13) FMA8(14) FMA8(15)                               \
            const float acc0 = (a0 + a1) + (a2 + a3);                         \
            const float acc1 = (d0 + d1) + (d2 + d3);                         \
            const float v0 = rcpf(1.0f + __expf(-acc0));       /* i or f */   \
            const float r1 = rcpf(1.0f + __expf(acc1 * nlm1));                \
            const float v1 = fmaf(k2, r1, k3);                 /* j or o */   \
            const float recv = dppmov<0xB1>(v0 * v1);  /* odd gets i*j */     \
            c1 = fmaf(c1, v0, recv);          /* odd: c1*f + i*j */           \
            const float h1v = ftanh(c1) * v1; /* odd: tanh(c1)*o */           \
            if (gg) h1row[(P) ^ 1][unit] = h1v;                               \
        }                                                                     \
        if ((t) >= 1 && (t) <= TT) {                                          \
            const float hm = h1row[P][lane];                                  \
            const float sA = wave_sum63(hm * w2a);                            \
            const float sB = wave_sum63(hm * w2b);                            \
            if (lane == 63) {                                                 \
                zp[((t) - 1) & 3][(wave << 1) + 0] = sA;                      \
                zp[((t) - 1) & 3][(wave << 1) + 1] = sB;                      \
            }                                                                 \
        }                                                                     \
        if (wave == 1 && lane == 0 && (t) >= 2 && (t) <= TT + 1) {            \
            const int st = (t) - 2;                                           \
            const float4 z4 = *(const float4*)zp[st & 3];                     \
            const float zi = z4.x + fmaf(h2, w2h0, b20);                      \
            const float zj = z4.y + fmaf(h2, w2h1, b21);                      \
            const float zf = z4.z + fmaf(h2, w2h2, b22);                      \
            const float zo = z4.w + fmaf(h2, w2h3, b23);                      \
            c2 = c2 * fsig(zf + 1.0f) + fsig(zi) * ftanh(zj);                 \
            h2 = ftanh(c2) * fsig(zo);                                        \
            h2buf[(st >> 6) & 1][st & 63] = h2;                               \
        }                                                                     \
        __syncthreads();                                                      \
        if (wave == 0 && (t) >= 66 && ((t) & 63) == 2) {                      \
            const int blk = ((t) - 66) >> 6;                                  \
            outb[(blk << 6) + lane] = h2buf[blk & 1][lane];                   \
        }                                                                     \
    }

#define FMA8(q)                                                               \
    {                                                                         \
        const float h_0 = hr[4*(q)+0], h_1 = hr[4*(q)+1];                     \
        const float h_2 = hr[4*(q)+2], h_3 = hr[4*(q)+3];                     \
        a0 = fmaf(h_0, ax##q, a0); d0 = fmaf(h_0, bx##q, d0);                 \
        a1 = fmaf(h_1, ay##q, a1); d1 = fmaf(h_1, by##q, d1);                 \
        a2 = fmaf(h_2, az##q, a2); d2 = fmaf(h_2, bz##q, d2);                 \
        a3 = fmaf(h_3, aw##q, a3); d3 = fmaf(h_3, bw##q, d3);                 \
    }

    for (int it = 0; it <= TT + 2; it += 2) {
        const float2 x2 = *(const float2*)&xall[it];
        STEP(0, it,     x2.x)
        STEP(1, it + 1, x2.y)
    }
#undef FMA8
#undef STEP
}

extern "C" void kernel_launch(void* const* d_in, const int* in_sizes, int n_in,
                              void* d_out, int out_size, void* d_ws, size_t ws_size,
                              hipStream_t stream)
{
    const float* x  = (const float*)d_in[0];
    const float* W1 = (const float*)d_in[1];
    const float* b1 = (const float*)d_in[2];
    const float* W2 = (const float*)d_in[3];
    const float* b2 = (const float*)d_in[4];
    float* out = (float*)d_out;
    lstm2_kernel<<<NB, 128, 0, stream>>>(x, W1, b1, W2, b2, out);
}

// Round 11
// 1531.872 us; speedup vs baseline: 1.9544x; 1.2403x over previous
//
#include <hip/hip_runtime.h>

#define TT 2048
#define NB 512

typedef float v2f __attribute__((ext_vector_type(2)));

__device__ __forceinline__ v2f mk2(float a, float b) { v2f r; r.x = a; r.y = b; return r; }
__device__ __forceinline__ float rcpf(float x) { return __builtin_amdgcn_rcpf(x); }
__device__ __forceinline__ float fsig(float x) { return rcpf(1.0f + __expf(-x)); }
__device__ __forceinline__ float ftanh(float x) {
    return fmaf(2.0f, rcpf(1.0f + __expf(-2.0f * x)), -1.0f);
}

template<int C>
__device__ __forceinline__ float dppmov(float s) {
    return __int_as_float(__builtin_amdgcn_update_dpp(
        __float_as_int(s), __float_as_int(s), C, 0xF, 0xF, false));
}
// Full wave64 sum, result in lane 63 (verified R6).
__device__ __forceinline__ float wave_sum63(float s) {
    s += dppmov<0x111>(s); s += dppmov<0x112>(s); s += dppmov<0x114>(s);
    s += dppmov<0x118>(s); s += dppmov<0x142>(s); s += dppmov<0x143>(s);
    return s;
}
template<int Q>
__device__ __forceinline__ float qbcast(float x) {
    return __int_as_float(__builtin_amdgcn_update_dpp(
        __float_as_int(x), __float_as_int(x), Q * 0x55, 0xF, 0xF, false));
}

// 512 blocks x 8 waves (512 thr), 1 batch elem/block, 2 blocks/CU = 4 w/SIMD.
// Lane = 8*u' + 4*h + g: wave owns units 8w..8w+7; h splits K (32 rows each,
// 16 float2 packed weights -> v_pk_fma_f32); quad = 4 gates of (unit,half).
// R10 BUGFIX: half-combine direction was swapped. DPP semantics (proven by
// wave_sum63 since R6): row_shr:N = dst lane i <- lane i-N; row_shl:N =
// <- lane i+N. h=0's partner is at +4 (row_shl:4), h=1's at -4 (row_shr:4).
// R10 selected (h ? tshl : tshr); correct is (h ? tshr : tshl).
// R8's two killers remain fixed: bank-disjoint halves (words 0..31 / 48..79)
// and VALU-only gate exchange (quad_perm). ONE barrier/step. Layer-2: DPP
// wave_sum on waves 0-3 (gate=wave), scalar chain wave7/lane0 (2-lag), h2
// staged and flushed coalesced every 64 steps by wave 4.
__global__ __launch_bounds__(512)
__attribute__((amdgpu_waves_per_eu(4, 4)))
void lstm2_kernel(const float* __restrict__ x,
                  const float* __restrict__ W1,
                  const float* __restrict__ b1,
                  const float* __restrict__ W2,
                  const float* __restrict__ b2,
                  float* __restrict__ out)
{
    __shared__ __align__(16) float xall[TT + 4];
    __shared__ __align__(16) float h1x[2][80];   // halves at [0..31],[48..79]
    __shared__ __align__(16) float zp[4][4];     // layer-2 partial ring
    __shared__ __align__(16) float h2buf[2][64]; // h2 staging ring

    const int tid  = threadIdx.x;
    const int wave = tid >> 6;
    const int lane = tid & 63;
    const int b    = blockIdx.x;

    for (int i = tid; i < TT; i += 512) xall[i] = x[b * TT + i];

    const int u    = lane >> 3;          // unit-in-wave 0..7
    const int h    = (lane >> 2) & 1;    // K-half
    const int g    = lane & 3;           // gate i,j,f,o
    const int unit = (wave << 3) + u;    // global unit 0..63
    const int col  = (g << 6) + unit;    // W1 (65,256) column

    // 16 packed float2 weights: rows 1+32h+2k, 2+32h+2k of this column.
#define DECLW(k) const v2f wp##k = mk2(W1[(1 + 32*h + 2*(k)) * 256 + col], \
                                       W1[(2 + 32*h + 2*(k)) * 256 + col]);
    DECLW(0)  DECLW(1)  DECLW(2)  DECLW(3)
    DECLW(4)  DECLW(5)  DECLW(6)  DECLW(7)
    DECLW(8)  DECLW(9)  DECLW(10) DECLW(11)
    DECLW(12) DECLW(13) DECLW(14) DECLW(15)
#undef DECLW

    const float w0x   = (h == 0) ? W1[col] : 0.0f;   // x-part (half 0 only)
    const float biasF = (h == 0) ? (b1[col] + ((g == 2) ? 1.0f : 0.0f)) : 0.0f;
    const float nlm   = (g == 1) ? -2.0f : -1.0f;
    const bool  isj   = (g == 1);

    const float w2g  = W2[lane * 4 + (wave & 3)];    // waves 0-3 use gate=wave
    const float w2h0 = W2[256], w2h1 = W2[257], w2h2 = W2[258], w2h3 = W2[259];
    const float b20 = b2[0], b21 = b2[1], b22 = b2[2], b23 = b2[3];

    float c1 = 0.0f;                 // redundant per unit-octet
    float c2 = 0.0f, h2v = 0.0f;     // layer-2 state (wave7/lane0)

    const int hbase = h * 48;                          // own half's LDS base
    const int ridx  = lane + ((lane >> 5) << 4);       // padded read index
    const int widx  = (unit < 32) ? unit : unit + 16;  // padded write index

    if (tid < 160) ((float*)h1x)[tid] = 0.0f;
    __syncthreads();

    float* __restrict__ outb = out + b * TT;

#define STEP(P, t, xv)                                                        \
    {                                                                         \
        if ((t) < TT) {                                                       \
            const float4* hp = (const float4*)&h1x[P][hbase];                 \
            const float4 q0 = hp[0], q1 = hp[1], q2 = hp[2], q3 = hp[3];      \
            const float4 q4 = hp[4], q5 = hp[5], q6 = hp[6], q7 = hp[7];      \
            v2f a0 = mk2(fmaf((xv), w0x, biasF), 0.0f);                       \
            v2f a1 = mk2(0.f, 0.f), a2 = mk2(0.f, 0.f), a3 = mk2(0.f, 0.f);  \
            a0 = __builtin_elementwise_fma(mk2(q0.x, q0.y), wp0,  a0);        \
            a1 = __builtin_elementwise_fma(mk2(q0.z, q0.w), wp1,  a1);        \
            a2 = __builtin_elementwise_fma(mk2(q1.x, q1.y), wp2,  a2);        \
            a3 = __builtin_elementwise_fma(mk2(q1.z, q1.w), wp3,  a3);        \
            a0 = __builtin_elementwise_fma(mk2(q2.x, q2.y), wp4,  a0);        \
            a1 = __builtin_elementwise_fma(mk2(q2.z, q2.w), wp5,  a1);        \
            a2 = __builtin_elementwise_fma(mk2(q3.x, q3.y), wp6,  a2);        \
            a3 = __builtin_elementwise_fma(mk2(q3.z, q3.w), wp7,  a3);        \
            a0 = __builtin_elementwise_fma(mk2(q4.x, q4.y), wp8,  a0);        \
            a1 = __builtin_elementwise_fma(mk2(q4.z, q4.w), wp9,  a1);        \
            a2 = __builtin_elementwise_fma(mk2(q5.x, q5.y), wp10, a2);        \
            a3 = __builtin_elementwise_fma(mk2(q5.z, q5.w), wp11, a3);        \
            a0 = __builtin_elementwise_fma(mk2(q6.x, q6.y), wp12, a0);        \
            a1 = __builtin_elementwise_fma(mk2(q6.z, q6.w), wp13, a1);        \
            a2 = __builtin_elementwise_fma(mk2(q7.x, q7.y), wp14, a2);        \
            a3 = __builtin_elementwise_fma(mk2(q7.z, q7.w), wp15, a3);        \
            const v2f sv = (a0 + a1) + (a2 + a3);                             \
            const float zh = sv.x + sv.y;                                     \
            const float tshr = dppmov<0x114>(zh);   /* from lane i-4 */       \
            const float tshl = dppmov<0x104>(zh);   /* from lane i+4 */       \
            const float zfull = zh + (h ? tshr : tshl);  /* FIXED swap */     \
            const float e = __expf(zfull * nlm);                              \
            const float r = rcpf(1.0f + e);                                   \
            const float v = isj ? fmaf(2.0f, r, -1.0f) : r;                   \
            const float gi = qbcast<0>(v), gj = qbcast<1>(v);                 \
            const float gf = qbcast<2>(v), go = qbcast<3>(v);                 \
            c1 = fmaf(c1, gf, gi * gj);                                       \
            const float h1v = ftanh(c1) * go;                                 \
            if ((lane & 7) == 0) h1x[(P) ^ 1][widx] = h1v;                    \
        }                                                                     \
        if (wave < 4 && (t) >= 1 && (t) <= TT) {                              \
            const float s = wave_sum63(h1x[P][ridx] * w2g);                   \
            if (lane == 63) zp[((t) - 1) & 3][wave] = s;                      \
        }                                                                     \
        if (wave == 7 && lane == 0 && (t) >= 2 && (t) <= TT + 1) {            \
            const int st = (t) - 2;                                           \
            const float4 z4 = *(const float4*)zp[st & 3];                     \
            const float zi = z4.x + fmaf(h2v, w2h0, b20);                     \
            const float zj = z4.y + fmaf(h2v, w2h1, b21);                     \
            const float zf = z4.z + fmaf(h2v, w2h2, b22);                     \
            const float zo = z4.w + fmaf(h2v, w2h3, b23);                     \
            c2 = c2 * fsig(zf + 1.0f) + fsig(zi) * ftanh(zj);                 \
            h2v = ftanh(c2) * fsig(zo);                                       \
            h2buf[(st >> 6) & 1][st & 63] = h2v;                              \
        }                                                                     \
        __syncthreads();                                                      \
        if (wave == 4 && (t) >= 66 && ((t) & 63) == 2) {                      \
            const int blk = ((t) - 66) >> 6;                                  \
            outb[(blk << 6) + lane] = h2buf[blk & 1][lane];                   \
        }                                                                     \
    }

    for (int it = 0; it <= TT + 2; it += 2) {
        const float2 x2 = *(const float2*)&xall[it];
        STEP(0, it,     x2.x)
        STEP(1, it + 1, x2.y)
    }
#undef STEP
}

extern "C" void kernel_launch(void* const* d_in, const int* in_sizes, int n_in,
                              void* d_out, int out_size, void* d_ws, size_t ws_size,
                              hipStream_t stream)
{
    const float* x  = (const float*)d_in[0];
    const float* W1 = (const float*)d_in[1];
    const float* b1 = (const float*)d_in[2];
    const float* W2 = (const float*)d_in[3];
    const float* b2 = (const float*)d_in[4];
    float* out = (float*)d_out;
    lstm2_kernel<<<NB, 512, 0, stream>>>(x, W1, b1, W2, b2, out);
}